// Round 2
// baseline (238.200 us; speedup 1.0000x reference)
//
#include <hip/hip_runtime.h>

// out[r][c] = x[r][c] * diag[c]
// x: 16384 x 2048 fp32, diag: 2048 fp32. Memory-bound broadcast multiply.
//
// v2b: grid-stride at 2048 blocks (8 blocks/CU, full occupancy).
//  - stride = gridDim*blockDim = 524,288, a multiple of 512 (float4s per
//    row), so each thread's diag float4 index (i & 511) is LOOP-INVARIANT:
//    load diag once per thread instead of once per element.
//  - #pragma unroll 4 -> 4 independent x loads in flight per thread (ILP
//    on top of TLP); 16 iterations per thread, exactly divisible.
//  - nontemporal store for out: write-once data, don't let it fight the
//    x read stream for L2/L3 residency. Uses clang ext_vector_type(4)
//    (HIP float4 struct is rejected by the builtin).
using f4 = __attribute__((ext_vector_type(4))) float;

__global__ __launch_bounds__(256) void DiagonalDense_kernel(
    const f4* __restrict__ x,
    const f4* __restrict__ diag,
    f4* __restrict__ out,
    int n4) {
    const int i0     = blockIdx.x * blockDim.x + threadIdx.x;
    const int stride = gridDim.x * blockDim.x;   // multiple of 512 by launch config

    // 2048 cols / 4 = 512 float4 per row; invariant across the strided loop.
    const f4 dv = diag[i0 & 511];

    #pragma unroll 4
    for (int i = i0; i < n4; i += stride) {
        f4 xv = x[i];
        f4 ov = xv * dv;                      // elementwise on ext_vector
        __builtin_nontemporal_store(ov, &out[i]);
    }
}

extern "C" void kernel_launch(void* const* d_in, const int* in_sizes, int n_in,
                              void* d_out, int out_size, void* d_ws, size_t ws_size,
                              hipStream_t stream) {
    const f4* x    = (const f4*)d_in[0];   // 16384*2048 fp32
    const f4* diag = (const f4*)d_in[1];   // 2048 fp32
    f4* out        = (f4*)d_out;

    const int n  = out_size;       // 33,554,432 floats
    const int n4 = n / 4;          // 8,388,608 float4s (exactly divisible)

    const int block = 256;
    const int grid  = 2048;        // stride 524,288 (multiple of 512);
                                   // 16 iterations/thread, zero remainder
    DiagonalDense_kernel<<<grid, block, 0, stream>>>(x, diag, out, n4);
}

// Round 3
// 237.166 us; speedup vs baseline: 1.0044x; 1.0044x over previous
//
#include <hip/hip_runtime.h>

// out[r][c] = x[r][c] * diag[c]
// x: 16384 x 2048 fp32, diag: 2048 fp32. Memory-bound broadcast multiply.
//
// v3: v2b minus the nontemporal store (that was the regression: nt bypasses
// L2/L3, but L3 absorbs half our read traffic and defers write-back past
// the dispatch window; forcing writes straight to HBM serialized the kernel
// on the store path, 88 us vs ~61 us for v1).
//  - grid-stride at 2048 blocks (8 blocks/CU, 32 waves/CU theoretical).
//  - stride = 524,288 (multiple of 512 float4s/row) -> diag index (i & 511)
//    is loop-invariant: one diag load per thread.
//  - #pragma unroll 4 -> 4 independent x loads in flight per thread.
//  - plain stores: let out land dirty in L2/L3, write-back overlaps.
using f4 = __attribute__((ext_vector_type(4))) float;

__global__ __launch_bounds__(256) void DiagonalDense_kernel(
    const f4* __restrict__ x,
    const f4* __restrict__ diag,
    f4* __restrict__ out,
    int n4) {
    const int i0     = blockIdx.x * blockDim.x + threadIdx.x;
    const int stride = gridDim.x * blockDim.x;   // multiple of 512 by launch config

    // 2048 cols / 4 = 512 float4 per row; invariant across the strided loop.
    const f4 dv = diag[i0 & 511];

    #pragma unroll 4
    for (int i = i0; i < n4; i += stride) {
        f4 xv = x[i];
        out[i] = xv * dv;
    }
}

extern "C" void kernel_launch(void* const* d_in, const int* in_sizes, int n_in,
                              void* d_out, int out_size, void* d_ws, size_t ws_size,
                              hipStream_t stream) {
    const f4* x    = (const f4*)d_in[0];   // 16384*2048 fp32
    const f4* diag = (const f4*)d_in[1];   // 2048 fp32
    f4* out        = (f4*)d_out;

    const int n  = out_size;       // 33,554,432 floats
    const int n4 = n / 4;          // 8,388,608 float4s (exactly divisible)

    const int block = 256;
    const int grid  = 2048;        // stride 524,288 (multiple of 512);
                                   // 16 iterations/thread, zero remainder
    DiagonalDense_kernel<<<grid, block, 0, stream>>>(x, diag, out, n4);
}

// Round 4
// 230.023 us; speedup vs baseline: 1.0356x; 1.0311x over previous
//
#include <hip/hip_runtime.h>

// out[r][c] = x[r][c] * diag[c]
// x: 16384 x 2048 fp32, diag: 2048 fp32. Memory-bound broadcast multiply.
//
// v4: contiguous block tiles + per-thread ILP (v2/v3's 8MiB-stride
// grid-stride was the regression: 2.3 TB/s vs v1's ~3.3 TB/s).
//  - each block owns a contiguous 2048-float4 (32 KiB) tile: the machine
//    sweeps memory linearly like v1.
//  - each thread: 8 float4 loads (blockDim stride, 1 KiB-contiguous per
//    wave access) ALL issued before the first store -> 8-deep MLP and
//    read-burst/write-burst batching (fewer HBM read<->write turnarounds).
//  - tile base % 2048 == 0 -> diag index is (j&1)*256 + t: exactly two
//    diag registers per thread, loaded once.
using f4 = __attribute__((ext_vector_type(4))) float;

constexpr int BLOCK = 256;
constexpr int K     = 8;             // float4s per thread
constexpr int TILE  = BLOCK * K;     // 2048 float4s = 4 rows = 32 KiB

__global__ __launch_bounds__(BLOCK) void DiagonalDense_kernel(
    const f4* __restrict__ x,
    const f4* __restrict__ diag,
    f4* __restrict__ out) {
    const int t    = threadIdx.x;
    const int base = blockIdx.x * TILE;

    // (base + j*BLOCK + t) & 511 == (j&1)*256 + t  (base is 2048-aligned)
    const f4 dv0 = diag[t];          // even j
    const f4 dv1 = diag[t + 256];    // odd j

    f4 r[K];
    #pragma unroll
    for (int j = 0; j < K; ++j)
        r[j] = x[base + j * BLOCK + t];   // 8 independent loads in flight

    #pragma unroll
    for (int j = 0; j < K; ++j)
        out[base + j * BLOCK + t] = r[j] * ((j & 1) ? dv1 : dv0);
}

extern "C" void kernel_launch(void* const* d_in, const int* in_sizes, int n_in,
                              void* d_out, int out_size, void* d_ws, size_t ws_size,
                              hipStream_t stream) {
    const f4* x    = (const f4*)d_in[0];   // 16384*2048 fp32
    const f4* diag = (const f4*)d_in[1];   // 2048 fp32
    f4* out        = (f4*)d_out;

    const int n  = out_size;       // 33,554,432 floats
    const int n4 = n / 4;          // 8,388,608 float4s
    const int grid = n4 / TILE;    // 4096 blocks, exact (no remainder)

    DiagonalDense_kernel<<<grid, BLOCK, 0, stream>>>(x, diag, out);
}

// Round 5
// 226.520 us; speedup vs baseline: 1.0516x; 1.0155x over previous
//
#include <hip/hip_runtime.h>

// out[r][c] = x[r][c] * diag[c]
// x: 16384 x 2048 fp32, diag: 2048 fp32. Memory-bound broadcast multiply.
//
// v5: v4's contiguous 32 KiB block tiles, but with the 8-deep load burst
// ENFORCED. v4's VGPR_Count=28 proved the compiler re-interleaved the
// load/store loops into load->wait->store pairs (8 live f4 need 32 VGPRs),
// so per-thread MLP stayed ~1-2 and the kernel sat latency-bound at
// ~2.5 TB/s while the pure-write fill does 6.7 TB/s.
//  - 8 manually-named loads, then sched_barrier(0): loads can't sink,
//    stores can't hoist -> 8 global_load_dwordx4 in flight per thread
//    before the first s_waitcnt. Expect VGPR ~64 (still 8 waves/SIMD).
//  - tile base % 2048 == 0 -> diag regs are dv0/dv1 only, loaded once.
using f4 = __attribute__((ext_vector_type(4))) float;

constexpr int BLOCK = 256;
constexpr int K     = 8;             // float4s per thread
constexpr int TILE  = BLOCK * K;     // 2048 float4s = 4 rows = 32 KiB

__global__ __launch_bounds__(BLOCK) void DiagonalDense_kernel(
    const f4* __restrict__ x,
    const f4* __restrict__ diag,
    f4* __restrict__ out) {
    const int t    = threadIdx.x;
    const int base = blockIdx.x * TILE + t;

    // (base + j*BLOCK) & 511 == (j&1)*256 + t  (tile base is 2048-aligned)
    const f4 dv0 = diag[t];          // even j
    const f4 dv1 = diag[t + 256];    // odd j

    // ---- load cluster: 8 independent reads, all issued first ----
    f4 r0 = x[base + 0 * BLOCK];
    f4 r1 = x[base + 1 * BLOCK];
    f4 r2 = x[base + 2 * BLOCK];
    f4 r3 = x[base + 3 * BLOCK];
    f4 r4 = x[base + 4 * BLOCK];
    f4 r5 = x[base + 5 * BLOCK];
    f4 r6 = x[base + 6 * BLOCK];
    f4 r7 = x[base + 7 * BLOCK];

    __builtin_amdgcn_sched_barrier(0);   // pin: no store hoists above, no load sinks below

    // ---- mul + store cluster ----
    out[base + 0 * BLOCK] = r0 * dv0;
    out[base + 1 * BLOCK] = r1 * dv1;
    out[base + 2 * BLOCK] = r2 * dv0;
    out[base + 3 * BLOCK] = r3 * dv1;
    out[base + 4 * BLOCK] = r4 * dv0;
    out[base + 5 * BLOCK] = r5 * dv1;
    out[base + 6 * BLOCK] = r6 * dv0;
    out[base + 7 * BLOCK] = r7 * dv1;
}

extern "C" void kernel_launch(void* const* d_in, const int* in_sizes, int n_in,
                              void* d_out, int out_size, void* d_ws, size_t ws_size,
                              hipStream_t stream) {
    const f4* x    = (const f4*)d_in[0];   // 16384*2048 fp32
    const f4* diag = (const f4*)d_in[1];   // 2048 fp32
    f4* out        = (f4*)d_out;

    const int n  = out_size;       // 33,554,432 floats
    const int n4 = n / 4;          // 8,388,608 float4s
    const int grid = n4 / TILE;    // 4096 blocks, exact (no remainder)

    DiagonalDense_kernel<<<grid, BLOCK, 0, stream>>>(x, diag, out);
}